// Round 13
// baseline (127.112 us; speedup 1.0000x reference)
//
#include <hip/hip_runtime.h>

// Problem constants
#define BB 2
#define TT 2048
#define CC 768
#define HH 12
#define DD 64
#define NN (BB*TT)            // 4096 rows
#define NQ (BB*HH*TT*DD)      // 3145728 elements per q/k/v tensor
#define WSZ (CC*CC)           // 589824 per weight
#define NCH 32                // chunks per chain
#define CL 64                 // chunk length (timesteps)
#define NCHUNKS (BB*HH*NCH)   // 768 total chunks

typedef __attribute__((ext_vector_type(8))) short short8;
typedef __attribute__((ext_vector_type(8))) unsigned short ushort8;
typedef __attribute__((ext_vector_type(4))) float f32x4;
typedef unsigned short u16;

// async global->LDS: 16B per lane, dest = uniform wave base + lane*16
#define GLOAD16(g, l)                                                        \
    __builtin_amdgcn_global_load_lds(                                        \
        (const __attribute__((address_space(1))) void*)(g),                  \
        (__attribute__((address_space(3))) void*)(l), 16, 0, 0)

__device__ __forceinline__ u16 f2b(float f) {
    unsigned int u = __builtin_bit_cast(unsigned int, f);
    unsigned int r = (u + 0x7FFFu + ((u >> 16) & 1u)) >> 16;
    return (u16)r;
}
__device__ __forceinline__ float b2f(u16 b) {
    unsigned int u = ((unsigned int)b) << 16;
    return __builtin_bit_cast(float, u);
}
// VALU-speed cross-lane add via DPP quad_perm. 0xB1=xor1, 0x4E=xor2.
// Butterfly: after both stages ALL 4 lanes of a quad hold the total.
template <int CTRL>
__device__ __forceinline__ float dpp_xadd(float x) {
    int y = __builtin_amdgcn_update_dpp(0, __builtin_bit_cast(int, x),
                                        CTRL, 0xF, 0xF, true);
    return x + __builtin_bit_cast(float, y);
}
// Swizzled LDS helpers for [64][64] bf16 row-major tiles (128B rows split in
// 8 x 16B chunks, phys_chunk = chunk ^ (row&7)) -> conflict-free ds_read_b128.
__device__ __forceinline__ void st_sw(u16* buf, int row, int col, u16 v) {
    buf[row * 64 + ((((col >> 3) ^ (row & 7)) << 3) | (col & 7))] = v;
}
__device__ __forceinline__ short8 ld_frag(const u16* buf, int row, int lc) {
    return *(const short8*)&buf[row * 64 + ((lc ^ (row & 7)) << 3)];
}
// plain row-major global fragment (row of 64 bf16, 16B chunk lc)
__device__ __forceinline__ short8 gfrag(const u16* base, int row, int lc) {
    return *(const short8*)&base[row * 64 + lc * 8];
}
// fp32 global 32B -> bf16x8 (for in-GEMM conversion staging)
__device__ __forceinline__ ushort8 ld_cvt8(const float* src) {
    float4 f0 = *(const float4*)src;
    float4 f1 = *(const float4*)(src + 4);
    ushort8 o;
    o[0] = f2b(f0.x); o[1] = f2b(f0.y); o[2] = f2b(f0.z); o[3] = f2b(f0.w);
    o[4] = f2b(f1.x); o[5] = f2b(f1.y); o[6] = f2b(f1.z); o[7] = f2b(f1.w);
    return o;
}

// ---------------------------------------------------------------------------
// Kernel 0: fp32 -> bf16 for Wq, Wk, Wv only (x and Wo are converted inline
// inside the GEMMs that consume them -- saves a full pass over x).
// ---------------------------------------------------------------------------
__global__ __launch_bounds__(256) void cvt3_kernel(
    const float* __restrict__ Wq, const float* __restrict__ Wk,
    const float* __restrict__ Wv,
    u16* __restrict__ wqb, u16* __restrict__ wkb, u16* __restrict__ wvb)
{
    const int seg = blockIdx.y;
    const float* s; u16* d;
    if      (seg == 0) { s = Wq; d = wqb; }
    else if (seg == 1) { s = Wk; d = wkb; }
    else               { s = Wv; d = wvb; }
    int i = blockIdx.x * 256 + threadIdx.x;   // WSZ/8 = 73728 = 288*256
    const float* p = s + (size_t)i * 8;
    ushort8 o;
#pragma unroll
    for (int j = 0; j < 8; ++j) o[j] = f2b(p[j]);
    *(ushort8*)(d + (size_t)i * 8) = o;
}

// ---------------------------------------------------------------------------
// Kernel 1: q/k/v projection, bf16 MFMA, bf16 output scattered to [B,H,T,D].
// r13: A-operand (x) read as RAW FP32, converted to bf16 in registers and
// ds_write'd to the same swizzled layout (bit-identical to the old
// cvt->gload path). B (weights) stays bf16 gload_lds. XCD-chunk swizzle kept.
// ---------------------------------------------------------------------------
__global__ __launch_bounds__(256) void proj_qkv_kernel(
    const float* __restrict__ xf,
    const u16* __restrict__ wq, const u16* __restrict__ wk,
    const u16* __restrict__ wv,
    u16* __restrict__ qo, u16* __restrict__ ko, u16* __restrict__ vo)
{
    const int bid = blockIdx.x;
    const int job = (bid & 7) * 72 + (bid >> 3);   // 576 = 8 XCD x 72
    const int mb = job / 18, rem = job % 18;
    const int z = rem / 6, nb = rem % 6;

    const u16* Bsel = (z == 0) ? wq : ((z == 1) ? wk : wv);
    u16* Osel       = (z == 0) ? qo : ((z == 1) ? ko : vo);

    const int m0 = mb * 128;
    const int n0 = nb * 128;
    const int tid = threadIdx.x, lane = tid & 63, wid = tid >> 6;
    const int wm = (wid >> 1) * 64, wn = (wid & 1) * 64;

    __shared__ u16 As[128 * 64];
    __shared__ u16 Bs[128 * 64];

    f32x4 acc[4][4];
#pragma unroll
    for (int a = 0; a < 4; ++a)
#pragma unroll
        for (int b = 0; b < 4; ++b) acc[a][b] = (f32x4){0.f, 0.f, 0.f, 0.f};

    for (int kt = 0; kt < CC; kt += 64) {
#pragma unroll
        for (int i = 0; i < 4; ++i) {
            int slot = i * 256 + tid;
            int row = slot >> 3, c = slot & 7;
            int gc = c ^ (row & 7);
            // A: fp32 x -> bf16 regs -> swizzled LDS (layout == gload path)
            ushort8 av = ld_cvt8(xf + (size_t)(m0 + row) * CC + kt + gc * 8);
            *(ushort8*)((char*)As + slot * 16) = av;
            // B: bf16 weights via async gload (pre-swizzled source)
            GLOAD16(Bsel + (size_t)(n0 + row) * CC + kt + gc * 8,
                    (char*)Bs + slot * 16);
        }
        asm volatile("s_waitcnt vmcnt(0)" ::: "memory");
        __syncthreads();

#pragma unroll
        for (int kh = 0; kh < 2; ++kh) {
            short8 af[4], bf[4];
            const int lc = kh * 4 + (lane >> 4);
#pragma unroll
            for (int mi = 0; mi < 4; ++mi) {
                int row = wm + mi * 16 + (lane & 15);
                af[mi] = *(const short8*)((const char*)As + row * 128
                                          + ((lc ^ (row & 7)) * 16));
            }
#pragma unroll
            for (int ni = 0; ni < 4; ++ni) {
                int row = wn + ni * 16 + (lane & 15);
                bf[ni] = *(const short8*)((const char*)Bs + row * 128
                                          + ((lc ^ (row & 7)) * 16));
            }
#pragma unroll
            for (int mi = 0; mi < 4; ++mi)
#pragma unroll
                for (int ni = 0; ni < 4; ++ni)
                    acc[mi][ni] = __builtin_amdgcn_mfma_f32_16x16x32_bf16(
                        af[mi], bf[ni], acc[mi][ni], 0, 0, 0);
        }
        __syncthreads();
    }

#pragma unroll
    for (int mi = 0; mi < 4; ++mi) {
#pragma unroll
        for (int ni = 0; ni < 4; ++ni) {
            int n = n0 + wn + ni * 16 + (lane & 15);
            int mbase = m0 + wm + mi * 16 + ((lane >> 4) << 2);
            int h = n >> 6, d = n & 63;
#pragma unroll
            for (int r = 0; r < 4; ++r) {
                int m = mbase + r;
                int b = m >> 11, t = m & 2047;
                Osel[(((size_t)b * HH + h) * TT + t) * DD + d] =
                    f2b(acc[mi][ni][r]);
            }
        }
    }
}

// ---------------------------------------------------------------------------
// Kernel 2 (prep, parallel over 768 chunks): MFMA-transpose Kt/Vt, register
// forward substitution, aliased LDS pool (48KB), 3 blocks/CU.
// (identical to round 10 -- known good)
// ---------------------------------------------------------------------------
__global__ __launch_bounds__(256, 3) void ttt_prep3_kernel(
    const u16* __restrict__ kb, const u16* __restrict__ vb,
    const float* __restrict__ lr_scale,
    u16* __restrict__ ubg, float* __restrict__ pfA, float* __restrict__ pfB,
    u16* __restrict__ mtng, u16* __restrict__ rtng)
{
    const int bx = blockIdx.x;
    const int bh = bx >> 5;
    const int h = bh % HH;
    const float lr = 0.01f * lr_scale[h];
    const u16* kc = kb + (size_t)bx * 4096;
    const u16* vc = vb + (size_t)bx * 4096;
    u16* ubc  = ubg + (size_t)bx * 4096;
    float* pfc = (bx < 384) ? pfA + (size_t)bx * 4096
                            : pfB + (size_t)(bx - 384) * 4096;
    u16* mtnc = mtng + (size_t)bx * 4096;
    u16* rtnc = rtng + (size_t)bx * 4096;

    const int tid = threadIdx.x, lane = tid & 63, wid = tid >> 6;
    const int wm = (wid >> 1) * 32, wn = (wid & 1) * 32;
    const int ar0 = wm + (lane & 15);
    const int br0 = wn + (lane & 15);
    const int lcb = lane >> 4;
    const int or0 = wm + ((lane >> 4) << 2);
    const int oc0 = wn + (lane & 15);

    __shared__ __align__(16) char pool[49152];
    u16* Kl  = (u16*)pool;
    u16* Vl  = (u16*)(pool + 8192);
    u16* KtB = (u16*)(pool + 16384);
    u16* VtB = (u16*)(pool + 24576);
    float (*As4)[4][16] = (float (*)[4][16])(pool + 32768);   // 16KB
    u16* Rb   = Kl;
    u16* Ub   = Vl;
    u16* TmpB = VtB;
    u16* Tb   = (u16*)(pool + 32768);
    u16* TmpA = (u16*)(pool + 40960);

    // ---- stage K, V (pre-swizzled source, linear LDS dest) ----
#pragma unroll
    for (int i = 0; i < 2; ++i) {
        int slot = i * 256 + tid;
        int row = slot >> 3, cc = slot & 7;
        int gc = cc ^ (row & 7);
        GLOAD16(kc + row * 64 + gc * 8, (char*)Kl + slot * 16);
        GLOAD16(vc + row * 64 + gc * 8, (char*)Vl + slot * 16);
    }
    asm volatile("s_waitcnt vmcnt(0)" ::: "memory");
    __syncthreads();                                            // b0

    // ---- phase 1: aA = K K^T ; aKt = I*K (=K^T); aVt = I*V (=V^T) ----
    {
        short8 idA[2][2];
#pragma unroll
        for (int mi = 0; mi < 2; ++mi)
#pragma unroll
            for (int kh = 0; kh < 2; ++kh) {
                short8 idf = {0, 0, 0, 0, 0, 0, 0, 0};
#pragma unroll
                for (int e = 0; e < 8; ++e)
                    if (kh * 32 + lcb * 8 + e == ar0 + mi * 16)
                        idf[e] = (short)0x3F80;   // bf16 1.0
                idA[mi][kh] = idf;
            }

        f32x4 aA[2][2], aKt[2][2], aVt[2][2];
#pragma unroll
        for (int a = 0; a < 2; ++a)
#pragma unroll
            for (int b = 0; b < 2; ++b) {
                aA[a][b]  = (f32x4){0.f, 0.f, 0.f, 0.f};
                aKt[a][b] = (f32x4){0.f, 0.f, 0.f, 0.f};
                aVt[a][b] = (f32x4){0.f, 0.f, 0.f, 0.f};
            }
#pragma unroll
        for (int kh = 0; kh < 2; ++kh) {
            short8 ka[2], kbb[2], vbb[2];
#pragma unroll
            for (int i = 0; i < 2; ++i) {
                ka[i]  = ld_frag(Kl, ar0 + i * 16, kh * 4 + lcb);
                kbb[i] = ld_frag(Kl, br0 + i * 16, kh * 4 + lcb);
                vbb[i] = ld_frag(Vl, br0 + i * 16, kh * 4 + lcb);
            }
#pragma unroll
            for (int mi = 0; mi < 2; ++mi)
#pragma unroll
                for (int ni = 0; ni < 2; ++ni) {
                    aA[mi][ni] = __builtin_amdgcn_mfma_f32_16x16x32_bf16(
                        ka[mi], kbb[ni], aA[mi][ni], 0, 0, 0);
                    aKt[mi][ni] = __builtin_amdgcn_mfma_f32_16x16x32_bf16(
                        idA[mi][kh], kbb[ni], aKt[mi][ni], 0, 0, 0);
                    aVt[mi][ni] = __builtin_amdgcn_mfma_f32_16x16x32_bf16(
                        idA[mi][kh], vbb[ni], aVt[mi][ni], 0, 0, 0);
                }
        }
#pragma unroll
        for (int mi = 0; mi < 2; ++mi)
#pragma unroll
            for (int ni = 0; ni < 2; ++ni)
#pragma unroll
                for (int r = 0; r < 4; ++r) {
                    int t = or0 + mi * 16 + r, s = oc0 + ni * 16;
                    As4[t][s & 3][s >> 2] =
                        (t > s) ? lr * aA[mi][ni][r] : 0.f;
                    st_sw(KtB, t, s, f2b(aKt[mi][ni][r]));  // Kt[dim][time]
                    st_sw(VtB, t, s, f2b(aVt[mi][ni][r]));  // Vt[dim][time]
                }
    }
    __syncthreads();                                            // b1

    // ---- register-resident forward substitution (b128 coefficient reads)
    const int j = wid * 16 + (lane >> 2), g = lane & 3;
    float Treg[16];
#pragma unroll
    for (int m = 0; m < 16; ++m) Treg[m] = 0.f;
#pragma unroll
    for (int t = 0; t < 64; ++t) {
        float sum = 0.f;
#pragma unroll
        for (int m4 = 0; m4 <= (t >> 4); ++m4) {
            float4 a4 = *(const float4*)&As4[t][g][m4 * 4];
            sum += a4.x * Treg[m4 * 4 + 0];
            sum += a4.y * Treg[m4 * 4 + 1];
            sum += a4.z * Treg[m4 * 4 + 2];
            sum += a4.w * Treg[m4 * 4 + 3];
        }
        sum = dpp_xadd<0xB1>(sum);
        sum = dpp_xadd<0x4E>(sum);
        float v = ((t == j) ? 1.f : 0.f) - sum;
        if ((t & 3) == g) Treg[t >> 2] = v;
    }
    __syncthreads();                                            // b2 (As4 dead)

#pragma unroll
    for (int m = 0; m < 16; ++m) st_sw(Tb, g + 4 * m, j, f2b(Treg[m]));
    __syncthreads();                                            // b3

    // ---- set1: R = lr*mfma(Kt,T); U = lr*mfma(Vt,T); Rtn = -lr*mfma(T,Kt)
    {
        f32x4 aR[2][2], aU[2][2], aRt[2][2];
#pragma unroll
        for (int a = 0; a < 2; ++a)
#pragma unroll
            for (int b = 0; b < 2; ++b) {
                aR[a][b]  = (f32x4){0.f, 0.f, 0.f, 0.f};
                aU[a][b]  = (f32x4){0.f, 0.f, 0.f, 0.f};
                aRt[a][b] = (f32x4){0.f, 0.f, 0.f, 0.f};
            }
#pragma unroll
        for (int kh = 0; kh < 2; ++kh) {
            short8 kta[2], vta[2], ta[2], tbf[2], ktb[2];
#pragma unroll
            for (int i = 0; i < 2; ++i) {
                kta[i] = ld_frag(KtB, ar0 + i * 16, kh * 4 + lcb);
                vta[i] = ld_frag(VtB, ar0 + i * 16, kh * 4 + lcb);
                ta[i]  = ld_frag(Tb,  ar0 + i * 16, kh * 4 + lcb);
                tbf[i] = ld_frag(Tb,  br0 + i * 16, kh * 4 + lcb);
                ktb[i] = ld_frag(KtB, br0 + i * 16, kh * 4 + lcb);
            }
#pragma unroll
            for (int mi = 0; mi < 2; ++mi)
#pragma unroll
                for (int ni = 0; ni < 2; ++ni) {
                    aR[mi][ni] = __builtin_amdgcn_mfma_f32_16x16x32_bf16(
                        kta[mi], tbf[ni], aR[mi][ni], 0, 0, 0);
                    aU[mi][ni] = __builtin_amdgcn_mfma_f32_16x16x32_bf16(
                        vta[mi], tbf[ni], aU[mi][ni], 0, 0, 0);
                    aRt[mi][ni] = __builtin_amdgcn_mfma_f32_16x16x32_bf16(
                        ta[mi], ktb[ni], aRt[mi][ni], 0, 0, 0);
                }
        }
#pragma unroll
        for (int mi = 0; mi < 2; ++mi)
#pragma unroll
            for (int ni = 0; ni < 2; ++ni) {
                u16 ue[4];
#pragma unroll
                for (int r = 0; r < 4; ++r) {
                    int ro = or0 + mi * 16 + r, co = oc0 + ni * 16;
                    st_sw(Rb, ro, co, f2b(lr * aR[mi][ni][r]));
                    ue[r] = f2b(lr * aU[mi][ni][r]);
                    st_sw(Ub, ro, co, ue[r]);
                    st_sw(TmpA, ro, co, f2b(-lr * aRt[mi][ni][r]));
                }
                uint2 uo;
                uo.x = (unsigned)ue[0] | ((unsigned)ue[1] << 16);
                uo.y = (unsigned)ue[2] | ((unsigned)ue[3] << 16);
                *(uint2*)&ubc[(size_t)((((wid * 2 + mi) * 2 + ni) * 64
                                        + lane) * 4)] = uo;
            }
    }
    __syncthreads();                                            // b4

    // ---- set2: Mtn = -mfma(Kt,R) -> TmpB ; P = mfma(U,Kt) -> global fp32
    {
        f32x4 aM[2][2], aP[2][2];
#pragma unroll
        for (int a = 0; a < 2; ++a)
#pragma unroll
            for (int b = 0; b < 2; ++b) {
                aM[a][b] = (f32x4){0.f, 0.f, 0.f, 0.f};
                aP[a][b] = (f32x4){0.f, 0.f, 0.f, 0.f};
            }
#pragma unroll
        for (int kh = 0; kh < 2; ++kh) {
            short8 kta[2], ua[2], rbb[2], ktb[2];
#pragma unroll
            for (int i = 0; i < 2; ++i) {
                kta[i] = ld_frag(KtB, ar0 + i * 16, kh * 4 + lcb);
                ua[i]  = ld_frag(Ub,  ar0 + i * 16, kh * 4 + lcb);
                rbb[i] = ld_frag(Rb,  br0 + i * 16, kh * 4 + lcb);
                ktb[i] = ld_frag(KtB, br0 + i * 16, kh * 4 + lcb);
            }
#pragma unroll
            for (int mi = 0; mi < 2; ++mi)
#pragma unroll
                for (int ni = 0; ni < 2; ++ni) {
                    aM[mi][ni] = __builtin_amdgcn_mfma_f32_16x16x32_bf16(
                        kta[mi], rbb[ni], aM[mi][ni], 0, 0, 0);
                    aP[mi][ni] = __builtin_amdgcn_mfma_f32_16x16x32_bf16(
                        ua[mi], ktb[ni], aP[mi][ni], 0, 0, 0);
                }
        }
#pragma unroll
        for (int mi = 0; mi < 2; ++mi)
#pragma unroll
            for (int ni = 0; ni < 2; ++ni) {
#pragma unroll
                for (int r = 0; r < 4; ++r)
                    st_sw(TmpB, or0 + mi * 16 + r, oc0 + ni * 16,
                          f2b(-aM[mi][ni][r]));
                *(f32x4*)&pfc[(size_t)((((wid * 2 + mi) * 2 + ni) * 64
                                        + lane) * 4)] = aP[mi][ni];
            }
    }
    __syncthreads();                                            // b5
    // disjoint wave pairs store Mtn (waves 0-1) and Rtn (waves 2-3)
    if (wid < 2) {
#pragma unroll
        for (int ni = 0; ni < 2; ++ni)
#pragma unroll
            for (int kh = 0; kh < 2; ++kh) {
                short8 v = ld_frag(TmpB, (wid & 1) * 32 + ni * 16 + (lane & 15),
                                   kh * 4 + lcb);
                *(short8*)&mtnc[(size_t)(((((wid & 1) * 2 + ni) * 2 + kh) * 64
                                          + lane) * 8)] = v;
            }
    } else {
#pragma unroll
        for (int ni = 0; ni < 2; ++ni)
#pragma unroll
            for (int kh = 0; kh < 2; ++kh) {
                short8 v = ld_frag(TmpA, (wid & 1) * 32 + ni * 16 + (lane & 15),
                                   kh * 4 + lcb);
                *(short8*)&rtnc[(size_t)(((((wid & 1) * 2 + ni) * 2 + kh) * 64
                                          + lane) * 8)] = v;
            }
    }
}

// ---------------------------------------------------------------------------
// Kernel 3 (seq): one block per chain; per chunk: store W_c, Delta = P_c +
// W_c*Mtn_c (acc-init P), accW += Delta. Wb double-buffered -> ONE barrier
// per chunk. (identical to round 10 -- known good)
// ---------------------------------------------------------------------------
__global__ __launch_bounds__(256, 1) void ttt_seq_kernel(
    u16* __restrict__ mtnW, const float* __restrict__ pfA,
    const float* __restrict__ pfB)
{
    const int bh = blockIdx.x;
    const int bx0 = bh * NCH;
    const int tid = threadIdx.x, lane = tid & 63, wid = tid >> 6;
    const int wm = (wid >> 1) * 32, wn = (wid & 1) * 32;
    const int ar0 = wm + (lane & 15);
    const int lcb = lane >> 4;
    const int or0 = wm + ((lane >> 4) << 2);
    const int oc0 = wn + (lane & 15);
    const int wn2 = wid & 1;

    __shared__ u16 Wb[2][4096];

    f32x4 accW[2][2];
#pragma unroll
    for (int a = 0; a < 2; ++a)
#pragma unroll
        for (int b = 0; b < 2; ++b) accW[a][b] = (f32x4){0.f, 0.f, 0.f, 0.f};

    auto ldMtn = [&](int c, short8 (&m)[2][2]) {
        const u16* mb = mtnW + (size_t)(bx0 + c) * 4096;
#pragma unroll
        for (int ni = 0; ni < 2; ++ni)
#pragma unroll
            for (int kh = 0; kh < 2; ++kh)
                m[ni][kh] = *(const short8*)&mb[(size_t)(
                    (((wn2 * 2 + ni) * 2 + kh) * 64 + lane) * 8)];
    };
    auto ldPf = [&](int c, f32x4 (&p)[2][2]) {
        int bx = bx0 + c;
        const float* pb = (bx < 384) ? pfA + (size_t)bx * 4096
                                     : pfB + (size_t)(bx - 384) * 4096;
#pragma unroll
        for (int mi = 0; mi < 2; ++mi)
#pragma unroll
            for (int ni = 0; ni < 2; ++ni)
                p[mi][ni] = *(const f32x4*)&pb[(size_t)(
                    (((wid * 2 + mi) * 2 + ni) * 64 + lane) * 4)];
    };

    auto body = [&](int c, short8 (&cm)[2][2], f32x4 (&cp)[2][2],
                    short8 (&nm)[2][2], f32x4 (&np)[2][2]) {
        asm volatile("s_waitcnt vmcnt(0)" ::: "memory");
        u16* wcp = mtnW + (size_t)(bx0 + c) * 4096;
        u16* wl = &Wb[c & 1][0];
#pragma unroll
        for (int mi = 0; mi < 2; ++mi)
#pragma unroll
            for (int ni = 0; ni < 2; ++ni)
#pragma unroll
                for (int r = 0; r < 4; ++r) {
                    u16 v = f2b(accW[mi][ni][r]);
                    wcp[(or0 + mi * 16 + r) * 64 + oc0 + ni * 16] = v;
                    st_sw(wl, or0 + mi * 16 + r, oc0 + ni * 16, v);
                }
        if (c + 1 < NCH) { ldMtn(c + 1, nm); ldPf(c + 1, np); }
        __syncthreads();
        short8 wf[2][2];
#pragma unroll
        for (int mi = 0; mi < 2; ++mi)
#pragma unroll
            for (int kh = 0; kh < 2; ++kh)
                wf[mi][kh] = ld_frag(wl, ar0 + mi * 16, kh * 4 + lcb);
#pragma unroll
        for (int mi = 0; mi < 2; ++mi)
#pragma unroll
            for (int ni = 0; ni < 2; ++ni) {
                f32x4 d = cp[mi][ni];
#pragma unroll
                for (int kh = 0; kh < 2; ++kh)
                    d = __builtin_amdgcn_mfma_f32_16x16x32_bf16(
                        wf[mi][kh], cm[ni][kh], d, 0, 0, 0);
                accW[mi][ni] = accW[mi][ni] + d;
            }
        // no trailing barrier: next chunk writes the OTHER Wb buffer
    };

    short8 mA[2][2], mB[2][2];
    f32x4 pA[2][2], pB[2][2];
    ldMtn(0, mA); ldPf(0, pA);
    for (int c = 0; c < NCH; c += 2) {
        body(c,     mA, pA, mB, pB);
        body(c + 1, mB, pB, mA, pA);
    }
}

// ---------------------------------------------------------------------------
// Kernel 4 (outgen, parallel over 768 chunks):
//   S = stril(Q K^T); Etn = U + W * Rtn; Out = Q W^T + S Etn^T -> hidden.
// (identical to round 10 -- known good)
// ---------------------------------------------------------------------------
__global__ __launch_bounds__(256) void ttt_outgen_kernel(
    const u16* __restrict__ qb, const u16* __restrict__ kb,
    const u16* __restrict__ wcg, const u16* __restrict__ rtng,
    const u16* __restrict__ ubg, u16* __restrict__ hid)
{
    const int bx = blockIdx.x;
    const int bh = bx >> 5, c = bx & 31;
    const int b = bh / HH, h = bh % HH;
    const u16* qc = qb + (size_t)bx * 4096;
    const u16* kc = kb + (size_t)bx * 4096;
    const u16* wcc = wcg + (size_t)bx * 4096;
    const u16* rtnc = rtng + (size_t)bx * 4096;
    const u16* ubc = ubg + (size_t)bx * 4096;
    u16* hch = hid + (size_t)b * TT * CC + h * DD;

    const int tid = threadIdx.x, lane = tid & 63, wid = tid >> 6;
    const int wm = (wid >> 1) * 32, wn = (wid & 1) * 32;
    const int ar0 = wm + (lane & 15);
    const int br0 = wn + (lane & 15);
    const int lcb = lane >> 4;
    const int or0 = wm + ((lane >> 4) << 2);
    const int oc0 = wn + (lane & 15);
    const int wn2 = wid & 1;

    __shared__ u16 Sl[4096], El[4096];

    short8 Qa[2][2], Kb2[2][2];
#pragma unroll
    for (int i = 0; i < 2; ++i)
#pragma unroll
        for (int kh = 0; kh < 2; ++kh) {
            Qa[i][kh]  = gfrag(qc, ar0 + i * 16, kh * 4 + lcb);
            Kb2[i][kh] = gfrag(kc, br0 + i * 16, kh * 4 + lcb);
        }
    f32x4 aS[2][2];
#pragma unroll
    for (int a = 0; a < 2; ++a)
#pragma unroll
        for (int d = 0; d < 2; ++d) aS[a][d] = (f32x4){0.f, 0.f, 0.f, 0.f};
#pragma unroll
    for (int kh = 0; kh < 2; ++kh)
#pragma unroll
        for (int mi = 0; mi < 2; ++mi)
#pragma unroll
            for (int ni = 0; ni < 2; ++ni)
                aS[mi][ni] = __builtin_amdgcn_mfma_f32_16x16x32_bf16(
                    Qa[mi][kh], Kb2[ni][kh], aS[mi][ni], 0, 0, 0);
#pragma unroll
    for (int mi = 0; mi < 2; ++mi)
#pragma unroll
        for (int ni = 0; ni < 2; ++ni)
#pragma unroll
            for (int r = 0; r < 4; ++r) {
                int t = or0 + mi * 16 + r, s = oc0 + ni * 16;
                st_sw(Sl, t, s, f2b((t > s) ? aS[mi][ni][r] : 0.f));
            }

    f32x4 aE[2][2];
#pragma unroll
    for (int mi = 0; mi < 2; ++mi)
#pragma unroll
        for (int ni = 0; ni < 2; ++ni) {
            uint2 uu = *(const uint2*)&ubc[(size_t)(
                (((wid * 2 + mi) * 2 + ni) * 64 + lane) * 4)];
            f32x4 e;
            e[0] = b2f((u16)(uu.x & 0xFFFF)); e[1] = b2f((u16)(uu.x >> 16));
            e[2] = b2f((u16)(uu.y & 0xFFFF)); e[3] = b2f((u16)(uu.y >> 16));
            aE[mi][ni] = e;
        }
    short8 Wa[2][2], Rtb[2][2];
#pragma unroll
    for (int i = 0; i < 2; ++i)
#pragma unroll
        for (int kh = 0; kh < 2; ++kh) {
            Wa[i][kh] = gfrag(wcc, ar0 + i * 16, kh * 4 + lcb);
            Rtb[i][kh] = *(const short8*)&rtnc[(size_t)(
                (((wn2 * 2 + i) * 2 + kh) * 64 + lane) * 8)];
        }
#pragma unroll
    for (int kh = 0; kh < 2; ++kh)
#pragma unroll
        for (int mi = 0; mi < 2; ++mi)
#pragma unroll
            for (int ni = 0; ni < 2; ++ni)
                aE[mi][ni] = __builtin_amdgcn_mfma_f32_16x16x32_bf16(
                    Wa[mi][kh], Rtb[ni][kh], aE[mi][ni], 0, 0, 0);
#pragma unroll
    for (int mi = 0; mi < 2; ++mi)
#pragma unroll
        for (int ni = 0; ni < 2; ++ni)
#pragma unroll
            for (int r = 0; r < 4; ++r)
                st_sw(El, or0 + mi * 16 + r, oc0 + ni * 16,
                      f2b(aE[mi][ni][r]));
    __syncthreads();

    f32x4 aO[2][2];
#pragma unroll
    for (int a = 0; a < 2; ++a)
#pragma unroll
        for (int d = 0; d < 2; ++d) aO[a][d] = (f32x4){0.f, 0.f, 0.f, 0.f};
#pragma unroll
    for (int kh = 0; kh < 2; ++kh) {
        short8 Wb2[2], Sa[2], Eb[2];
#pragma unroll
        for (int i = 0; i < 2; ++i) {
            Wb2[i] = gfrag(wcc, br0 + i * 16, kh * 4 + lcb);
            Sa[i]  = ld_frag(Sl, ar0 + i * 16, kh * 4 + lcb);
            Eb[i]  = ld_frag(El, br0 + i * 16, kh * 4 + lcb);
        }
#pragma unroll
        for (int mi = 0; mi < 2; ++mi)
#pragma unroll
            for (int ni = 0; ni < 2; ++ni) {
                aO[mi][ni] = __builtin_amdgcn_mfma_f32_16x16x32_bf16(
                    Qa[mi][kh], Wb2[ni], aO[mi][ni], 0, 0, 0);
                aO[mi][ni] = __builtin_amdgcn_mfma_f32_16x16x32_bf16(
                    Sa[mi], Eb[ni], aO[mi][ni], 0, 0, 0);
            }
    }
#pragma unroll
    for (int mi = 0; mi < 2; ++mi)
#pragma unroll
        for (int ni = 0; ni < 2; ++ni)
#pragma unroll
            for (int r = 0; r < 4; ++r)
                hch[(size_t)(c * CL + or0 + mi * 16 + r) * CC
                    + oc0 + ni * 16] = f2b(aO[mi][ni][r]);
}

// ---------------------------------------------------------------------------
// Kernel 5: output projection (bf16 MFMA, fp32 row-major out).
// r13: B-operand (Wo) read as RAW FP32 + in-register conversion (same
// swizzled layout); A (hid bf16) stays gload_lds. XCD swizzle kept.
// ---------------------------------------------------------------------------
__global__ __launch_bounds__(256) void out_proj_kernel(
    const u16* __restrict__ hid, const float* __restrict__ wof,
    float* __restrict__ out)
{
    const int bid = blockIdx.x;
    const int job = (bid & 7) * 24 + (bid >> 3);
    const int m0 = (job / 6) * 128;
    const int n0 = (job % 6) * 128;
    const int tid = threadIdx.x, lane = tid & 63, wid = tid >> 6;
    const int wm = (wid >> 1) * 64, wn = (wid & 1) * 64;

    __shared__ u16 As[128 * 64];
    __shared__ u16 Bs[128 * 64];

    f32x4 acc[4][4];
#pragma unroll
    for (int a = 0; a < 4; ++a)
#pragma unroll
        for (int b = 0; b < 4; ++b) acc[a][b] = (f32x4){0.f, 0.f, 0.f, 0.f};

    for (int kt = 0; kt < CC; kt += 64) {
#pragma unroll
        for (int i = 0; i < 4; ++i) {
            int slot = i * 256 + tid;
            int row = slot >> 3, c = slot & 7;
            int gc = c ^ (row & 7);
            GLOAD16(hid + (size_t)(m0 + row) * CC + kt + gc * 8,
                    (char*)As + slot * 16);
            ushort8 bv = ld_cvt8(wof + (size_t)(n0 + row) * CC + kt + gc * 8);
            *(ushort8*)((char*)Bs + slot * 16) = bv;
        }
        asm volatile("s_waitcnt vmcnt(0)" ::: "memory");
        __syncthreads();

#pragma unroll
        for (int kh = 0; kh < 2; ++kh) {
            short8 af[4], bf[4];
            const int lc = kh * 4 + (lane >> 4);
#pragma unroll
            for (int mi = 0; mi < 4; ++mi) {
                int row = wm + mi * 16 + (lane & 15);
                af[mi] = *(const short8*)((const char*)As + row * 128
                                          + ((lc ^ (row & 7)) * 16));
            }
#pragma unroll
            for (int ni = 0; ni < 4; ++ni) {
                int row = wn + ni * 16 + (lane & 15);
                bf[ni] = *(const short8*)((const char*)Bs + row * 128
                                          + ((lc ^ (row & 7)) * 16));
            }
#pragma unroll
            for (int mi = 0; mi < 4; ++mi)
#pragma unroll
                for (int ni = 0; ni < 4; ++ni)
                    acc[mi][ni] = __builtin_amdgcn_mfma_f32_16x16x32_bf16(
                        af[mi], bf[ni], acc[mi][ni], 0, 0, 0);
        }
        __syncthreads();
    }

#pragma unroll
    for (int mi = 0; mi < 4; ++mi) {
#pragma unroll
        for (int ni = 0; ni < 4; ++ni) {
            int n = n0 + wn + ni * 16 + (lane & 15);
            int mbase = m0 + wm + mi * 16 + ((lane >> 4) << 2);
#pragma unroll
            for (int r = 0; r < 4; ++r)
                out[(size_t)(mbase + r) * CC + n] = acc[mi][ni][r];
        }
    }
}

// ---------------------------------------------------------------------------
extern "C" void kernel_launch(void* const* d_in, const int* in_sizes, int n_in,
                              void* d_out, int out_size, void* d_ws, size_t ws_size,
                              hipStream_t stream) {
    const float* x  = (const float*)d_in[0];
    const float* Wq = (const float*)d_in[1];
    const float* Wk = (const float*)d_in[2];
    const float* Wv = (const float*)d_in[3];
    const float* Wo = (const float*)d_in[4];
    const float* lr = (const float*)d_in[5];

    // workspace: 7*NQ + 4*WSZ u16. Aliases:
    //  slot2: vb -> Ub ; slot3: pfA(fp32) -> hid
    //  slot4: Mtn -> Wc ; slot6: pfB (fp32 half of P)
    u16* us   = (u16*)d_ws;
    u16* qb   = us;
    u16* kbw  = us + (size_t)NQ;
    u16* vbw  = us + (size_t)2 * NQ;    // -> Ub
    u16* xb   = us + (size_t)3 * NQ;    // -> pfA -> hid
    u16* mtnW = us + (size_t)4 * NQ;    // -> Wc
    u16* rtn  = us + (size_t)5 * NQ;
    float* pfB = (float*)(us + (size_t)6 * NQ);
    u16* wqb = us + (size_t)7 * NQ;
    u16* wkb = wqb + WSZ;
    u16* wvb = wkb + WSZ;
    u16* ub  = vbw;
    float* pfA = (float*)xb;
    u16* hid = xb;

    // 0) fp32 -> bf16 (weights for proj only; x and Wo converted in-GEMM)
    cvt3_kernel<<<dim3(WSZ / 8 / 256, 3), 256, 0, stream>>>(
        Wq, Wk, Wv, wqb, wkb, wvb);

    // 1) q/k/v projections (fp32 x in, bf16 out, [B,H,T,D], XCD swizzled)
    proj_qkv_kernel<<<dim3(576), 256, 0, stream>>>(
        x, wqb, wkb, wvb, qb, kbw, vbw);

    // 2) prep: per-chunk U, P, Mtn, Rtn (768 parallel blocks, 3 blk/CU)
    ttt_prep3_kernel<<<dim3(NCHUNKS), 256, 0, stream>>>(
        kbw, vbw, lr, ub, pfA, pfB, mtnW, rtn);

    // 3) seq: W-chain only, 24 blocks, 1 gemm + 1 barrier per chunk
    ttt_seq_kernel<<<dim3(BB * HH), 256, 0, stream>>>(mtnW, pfA, pfB);

    // 4) outgen: per-chunk hidden output (768 parallel blocks)
    ttt_outgen_kernel<<<dim3(NCHUNKS), 256, 0, stream>>>(
        qb, kbw, mtnW, rtn, ub, hid);

    // 5) output projection (fp32 Wo in, XCD swizzled)
    out_proj_kernel<<<dim3(192), 256, 0, stream>>>(
        hid, Wo, (float*)d_out);
}

// Round 14
// 103.101 us; speedup vs baseline: 1.2329x; 1.2329x over previous
//
#include <hip/hip_runtime.h>

// Problem constants
#define BB 2
#define TT 2048
#define CC 768
#define HH 12
#define DD 64
#define NN (BB*TT)            // 4096 rows
#define NQ (BB*HH*TT*DD)      // 3145728 elements per q/k/v tensor
#define WSZ (CC*CC)           // 589824 per weight
#define NCH 32                // chunks per chain
#define CL 64                 // chunk length (timesteps)
#define NCHUNKS (BB*HH*NCH)   // 768 total chunks

typedef __attribute__((ext_vector_type(8))) short short8;
typedef __attribute__((ext_vector_type(8))) unsigned short ushort8;
typedef __attribute__((ext_vector_type(4))) float f32x4;
typedef unsigned short u16;

// async global->LDS: 16B per lane, dest = uniform wave base + lane*16
#define GLOAD16(g, l)                                                        \
    __builtin_amdgcn_global_load_lds(                                        \
        (const __attribute__((address_space(1))) void*)(g),                  \
        (__attribute__((address_space(3))) void*)(l), 16, 0, 0)

__device__ __forceinline__ u16 f2b(float f) {
    unsigned int u = __builtin_bit_cast(unsigned int, f);
    unsigned int r = (u + 0x7FFFu + ((u >> 16) & 1u)) >> 16;
    return (u16)r;
}
__device__ __forceinline__ float b2f(u16 b) {
    unsigned int u = ((unsigned int)b) << 16;
    return __builtin_bit_cast(float, u);
}
// VALU-speed cross-lane add via DPP quad_perm. 0xB1=xor1, 0x4E=xor2.
// Butterfly: after both stages ALL 4 lanes of a quad hold the total.
template <int CTRL>
__device__ __forceinline__ float dpp_xadd(float x) {
    int y = __builtin_amdgcn_update_dpp(0, __builtin_bit_cast(int, x),
                                        CTRL, 0xF, 0xF, true);
    return x + __builtin_bit_cast(float, y);
}
// Swizzled LDS helpers for [64][64] bf16 row-major tiles (128B rows split in
// 8 x 16B chunks, phys_chunk = chunk ^ (row&7)) -> conflict-free ds_read_b128.
__device__ __forceinline__ void st_sw(u16* buf, int row, int col, u16 v) {
    buf[row * 64 + ((((col >> 3) ^ (row & 7)) << 3) | (col & 7))] = v;
}
__device__ __forceinline__ short8 ld_frag(const u16* buf, int row, int lc) {
    return *(const short8*)&buf[row * 64 + ((lc ^ (row & 7)) << 3)];
}
// plain row-major global fragment (row of 64 bf16, 16B chunk lc)
__device__ __forceinline__ short8 gfrag(const u16* base, int row, int lc) {
    return *(const short8*)&base[row * 64 + lc * 8];
}

// ---------------------------------------------------------------------------
// Kernel 0: fp32 -> bf16 for x, Wq, Wk, Wv, Wo.
// (separate streaming pass: converts x ONCE so proj's 6x reuse is bf16 —
//  r13's in-GEMM conversion doubled proj traffic and serialized staging)
// ---------------------------------------------------------------------------
__global__ __launch_bounds__(256) void cvt5_kernel(
    const float* __restrict__ x,  const float* __restrict__ Wq,
    const float* __restrict__ Wk, const float* __restrict__ Wv,
    const float* __restrict__ Wo,
    u16* __restrict__ xb, u16* __restrict__ wqb, u16* __restrict__ wkb,
    u16* __restrict__ wvb, u16* __restrict__ wob)
{
    const int seg = blockIdx.y;
    const float* s; u16* d; int n8;
    if      (seg == 0) { s = x;  d = xb;  n8 = NQ  / 8; }
    else if (seg == 1) { s = Wq; d = wqb; n8 = WSZ / 8; }
    else if (seg == 2) { s = Wk; d = wkb; n8 = WSZ / 8; }
    else if (seg == 3) { s = Wv; d = wvb; n8 = WSZ / 8; }
    else               { s = Wo; d = wob; n8 = WSZ / 8; }
    int i = blockIdx.x * 256 + threadIdx.x;
    if (i >= n8) return;
    const float* p = s + (size_t)i * 8;
    ushort8 o;
#pragma unroll
    for (int j = 0; j < 8; ++j) o[j] = f2b(p[j]);
    *(ushort8*)(d + (size_t)i * 8) = o;
}

// ---------------------------------------------------------------------------
// Kernel 1: q/k/v projection, bf16 MFMA, bf16 output scattered to [B,H,T,D].
// XCD-chunk swizzle (1-D grid, blockIdx remap only).
// ---------------------------------------------------------------------------
__global__ __launch_bounds__(256) void proj_qkv_kernel(
    const u16* __restrict__ xb,
    const u16* __restrict__ wq, const u16* __restrict__ wk,
    const u16* __restrict__ wv,
    u16* __restrict__ qo, u16* __restrict__ ko, u16* __restrict__ vo)
{
    const int bid = blockIdx.x;
    const int job = (bid & 7) * 72 + (bid >> 3);   // 576 = 8 XCD x 72
    const int mb = job / 18, rem = job % 18;
    const int z = rem / 6, nb = rem % 6;

    const u16* Bsel = (z == 0) ? wq : ((z == 1) ? wk : wv);
    u16* Osel       = (z == 0) ? qo : ((z == 1) ? ko : vo);

    const int m0 = mb * 128;
    const int n0 = nb * 128;
    const int tid = threadIdx.x, lane = tid & 63, wid = tid >> 6;
    const int wm = (wid >> 1) * 64, wn = (wid & 1) * 64;

    __shared__ u16 As[128 * 64];
    __shared__ u16 Bs[128 * 64];

    f32x4 acc[4][4];
#pragma unroll
    for (int a = 0; a < 4; ++a)
#pragma unroll
        for (int b = 0; b < 4; ++b) acc[a][b] = (f32x4){0.f, 0.f, 0.f, 0.f};

    for (int kt = 0; kt < CC; kt += 64) {
#pragma unroll
        for (int i = 0; i < 4; ++i) {
            int slot = i * 256 + tid;
            int row = slot >> 3, c = slot & 7;
            int gc = c ^ (row & 7);
            GLOAD16(xb   + (size_t)(m0 + row) * CC + kt + gc * 8,
                    (char*)As + slot * 16);
            GLOAD16(Bsel + (size_t)(n0 + row) * CC + kt + gc * 8,
                    (char*)Bs + slot * 16);
        }
        asm volatile("s_waitcnt vmcnt(0)" ::: "memory");
        __syncthreads();

#pragma unroll
        for (int kh = 0; kh < 2; ++kh) {
            short8 af[4], bf[4];
            const int lc = kh * 4 + (lane >> 4);
#pragma unroll
            for (int mi = 0; mi < 4; ++mi) {
                int row = wm + mi * 16 + (lane & 15);
                af[mi] = *(const short8*)((const char*)As + row * 128
                                          + ((lc ^ (row & 7)) * 16));
            }
#pragma unroll
            for (int ni = 0; ni < 4; ++ni) {
                int row = wn + ni * 16 + (lane & 15);
                bf[ni] = *(const short8*)((const char*)Bs + row * 128
                                          + ((lc ^ (row & 7)) * 16));
            }
#pragma unroll
            for (int mi = 0; mi < 4; ++mi)
#pragma unroll
                for (int ni = 0; ni < 4; ++ni)
                    acc[mi][ni] = __builtin_amdgcn_mfma_f32_16x16x32_bf16(
                        af[mi], bf[ni], acc[mi][ni], 0, 0, 0);
        }
        __syncthreads();
    }

#pragma unroll
    for (int mi = 0; mi < 4; ++mi) {
#pragma unroll
        for (int ni = 0; ni < 4; ++ni) {
            int n = n0 + wn + ni * 16 + (lane & 15);
            int mbase = m0 + wm + mi * 16 + ((lane >> 4) << 2);
            int h = n >> 6, d = n & 63;
#pragma unroll
            for (int r = 0; r < 4; ++r) {
                int m = mbase + r;
                int b = m >> 11, t = m & 2047;
                Osel[(((size_t)b * HH + h) * TT + t) * DD + d] =
                    f2b(acc[mi][ni][r]);
            }
        }
    }
}

// ---------------------------------------------------------------------------
// Kernel 2 (prep, parallel over 768 chunks): MFMA-transpose Kt/Vt, register
// forward substitution, aliased LDS pool (48KB), 3 blocks/CU.
// ---------------------------------------------------------------------------
__global__ __launch_bounds__(256, 3) void ttt_prep3_kernel(
    const u16* __restrict__ kb, const u16* __restrict__ vb,
    const float* __restrict__ lr_scale,
    u16* __restrict__ ubg, float* __restrict__ pfA, float* __restrict__ pfB,
    u16* __restrict__ mtng, u16* __restrict__ rtng)
{
    const int bx = blockIdx.x;
    const int bh = bx >> 5;
    const int h = bh % HH;
    const float lr = 0.01f * lr_scale[h];
    const u16* kc = kb + (size_t)bx * 4096;
    const u16* vc = vb + (size_t)bx * 4096;
    u16* ubc  = ubg + (size_t)bx * 4096;
    float* pfc = (bx < 384) ? pfA + (size_t)bx * 4096
                            : pfB + (size_t)(bx - 384) * 4096;
    u16* mtnc = mtng + (size_t)bx * 4096;
    u16* rtnc = rtng + (size_t)bx * 4096;

    const int tid = threadIdx.x, lane = tid & 63, wid = tid >> 6;
    const int wm = (wid >> 1) * 32, wn = (wid & 1) * 32;
    const int ar0 = wm + (lane & 15);
    const int br0 = wn + (lane & 15);
    const int lcb = lane >> 4;
    const int or0 = wm + ((lane >> 4) << 2);
    const int oc0 = wn + (lane & 15);

    __shared__ __align__(16) char pool[49152];
    u16* Kl  = (u16*)pool;
    u16* Vl  = (u16*)(pool + 8192);
    u16* KtB = (u16*)(pool + 16384);
    u16* VtB = (u16*)(pool + 24576);
    float (*As4)[4][16] = (float (*)[4][16])(pool + 32768);   // 16KB
    u16* Rb   = Kl;
    u16* Ub   = Vl;
    u16* TmpB = VtB;
    u16* Tb   = (u16*)(pool + 32768);
    u16* TmpA = (u16*)(pool + 40960);

    // ---- stage K, V (pre-swizzled source, linear LDS dest) ----
#pragma unroll
    for (int i = 0; i < 2; ++i) {
        int slot = i * 256 + tid;
        int row = slot >> 3, cc = slot & 7;
        int gc = cc ^ (row & 7);
        GLOAD16(kc + row * 64 + gc * 8, (char*)Kl + slot * 16);
        GLOAD16(vc + row * 64 + gc * 8, (char*)Vl + slot * 16);
    }
    asm volatile("s_waitcnt vmcnt(0)" ::: "memory");
    __syncthreads();                                            // b0

    // ---- phase 1: aA = K K^T ; aKt = I*K (=K^T); aVt = I*V (=V^T) ----
    {
        short8 idA[2][2];
#pragma unroll
        for (int mi = 0; mi < 2; ++mi)
#pragma unroll
            for (int kh = 0; kh < 2; ++kh) {
                short8 idf = {0, 0, 0, 0, 0, 0, 0, 0};
#pragma unroll
                for (int e = 0; e < 8; ++e)
                    if (kh * 32 + lcb * 8 + e == ar0 + mi * 16)
                        idf[e] = (short)0x3F80;   // bf16 1.0
                idA[mi][kh] = idf;
            }

        f32x4 aA[2][2], aKt[2][2], aVt[2][2];
#pragma unroll
        for (int a = 0; a < 2; ++a)
#pragma unroll
            for (int b = 0; b < 2; ++b) {
                aA[a][b]  = (f32x4){0.f, 0.f, 0.f, 0.f};
                aKt[a][b] = (f32x4){0.f, 0.f, 0.f, 0.f};
                aVt[a][b] = (f32x4){0.f, 0.f, 0.f, 0.f};
            }
#pragma unroll
        for (int kh = 0; kh < 2; ++kh) {
            short8 ka[2], kbb[2], vbb[2];
#pragma unroll
            for (int i = 0; i < 2; ++i) {
                ka[i]  = ld_frag(Kl, ar0 + i * 16, kh * 4 + lcb);
                kbb[i] = ld_frag(Kl, br0 + i * 16, kh * 4 + lcb);
                vbb[i] = ld_frag(Vl, br0 + i * 16, kh * 4 + lcb);
            }
#pragma unroll
            for (int mi = 0; mi < 2; ++mi)
#pragma unroll
                for (int ni = 0; ni < 2; ++ni) {
                    aA[mi][ni] = __builtin_amdgcn_mfma_f32_16x16x32_bf16(
                        ka[mi], kbb[ni], aA[mi][ni], 0, 0, 0);
                    aKt[mi][ni] = __builtin_amdgcn_mfma_f32_16x16x32_bf16(
                        idA[mi][kh], kbb[ni], aKt[mi][ni], 0, 0, 0);
                    aVt[mi][ni] = __builtin_amdgcn_mfma_f32_16x16x32_bf16(
                        idA[mi][kh], vbb[ni], aVt[mi][ni], 0, 0, 0);
                }
        }
#pragma unroll
        for (int mi = 0; mi < 2; ++mi)
#pragma unroll
            for (int ni = 0; ni < 2; ++ni)
#pragma unroll
                for (int r = 0; r < 4; ++r) {
                    int t = or0 + mi * 16 + r, s = oc0 + ni * 16;
                    As4[t][s & 3][s >> 2] =
                        (t > s) ? lr * aA[mi][ni][r] : 0.f;
                    st_sw(KtB, t, s, f2b(aKt[mi][ni][r]));  // Kt[dim][time]
                    st_sw(VtB, t, s, f2b(aVt[mi][ni][r]));  // Vt[dim][time]
                }
    }
    __syncthreads();                                            // b1

    // ---- register-resident forward substitution (b128 coefficient reads)
    const int j = wid * 16 + (lane >> 2), g = lane & 3;
    float Treg[16];
#pragma unroll
    for (int m = 0; m < 16; ++m) Treg[m] = 0.f;
#pragma unroll
    for (int t = 0; t < 64; ++t) {
        float sum = 0.f;
#pragma unroll
        for (int m4 = 0; m4 <= (t >> 4); ++m4) {
            float4 a4 = *(const float4*)&As4[t][g][m4 * 4];
            sum += a4.x * Treg[m4 * 4 + 0];
            sum += a4.y * Treg[m4 * 4 + 1];
            sum += a4.z * Treg[m4 * 4 + 2];
            sum += a4.w * Treg[m4 * 4 + 3];
        }
        sum = dpp_xadd<0xB1>(sum);
        sum = dpp_xadd<0x4E>(sum);
        float v = ((t == j) ? 1.f : 0.f) - sum;
        if ((t & 3) == g) Treg[t >> 2] = v;
    }
    __syncthreads();                                            // b2 (As4 dead)

#pragma unroll
    for (int m = 0; m < 16; ++m) st_sw(Tb, g + 4 * m, j, f2b(Treg[m]));
    __syncthreads();                                            // b3

    // ---- set1: R = lr*mfma(Kt,T); U = lr*mfma(Vt,T); Rtn = -lr*mfma(T,Kt)
    {
        f32x4 aR[2][2], aU[2][2], aRt[2][2];
#pragma unroll
        for (int a = 0; a < 2; ++a)
#pragma unroll
            for (int b = 0; b < 2; ++b) {
                aR[a][b]  = (f32x4){0.f, 0.f, 0.f, 0.f};
                aU[a][b]  = (f32x4){0.f, 0.f, 0.f, 0.f};
                aRt[a][b] = (f32x4){0.f, 0.f, 0.f, 0.f};
            }
#pragma unroll
        for (int kh = 0; kh < 2; ++kh) {
            short8 kta[2], vta[2], ta[2], tbf[2], ktb[2];
#pragma unroll
            for (int i = 0; i < 2; ++i) {
                kta[i] = ld_frag(KtB, ar0 + i * 16, kh * 4 + lcb);
                vta[i] = ld_frag(VtB, ar0 + i * 16, kh * 4 + lcb);
                ta[i]  = ld_frag(Tb,  ar0 + i * 16, kh * 4 + lcb);
                tbf[i] = ld_frag(Tb,  br0 + i * 16, kh * 4 + lcb);
                ktb[i] = ld_frag(KtB, br0 + i * 16, kh * 4 + lcb);
            }
#pragma unroll
            for (int mi = 0; mi < 2; ++mi)
#pragma unroll
                for (int ni = 0; ni < 2; ++ni) {
                    aR[mi][ni] = __builtin_amdgcn_mfma_f32_16x16x32_bf16(
                        kta[mi], tbf[ni], aR[mi][ni], 0, 0, 0);
                    aU[mi][ni] = __builtin_amdgcn_mfma_f32_16x16x32_bf16(
                        vta[mi], tbf[ni], aU[mi][ni], 0, 0, 0);
                    aRt[mi][ni] = __builtin_amdgcn_mfma_f32_16x16x32_bf16(
                        ta[mi], ktb[ni], aRt[mi][ni], 0, 0, 0);
                }
        }
#pragma unroll
        for (int mi = 0; mi < 2; ++mi)
#pragma unroll
            for (int ni = 0; ni < 2; ++ni) {
                u16 ue[4];
#pragma unroll
                for (int r = 0; r < 4; ++r) {
                    int ro = or0 + mi * 16 + r, co = oc0 + ni * 16;
                    st_sw(Rb, ro, co, f2b(lr * aR[mi][ni][r]));
                    ue[r] = f2b(lr * aU[mi][ni][r]);
                    st_sw(Ub, ro, co, ue[r]);
                    st_sw(TmpA, ro, co, f2b(-lr * aRt[mi][ni][r]));
                }
                uint2 uo;
                uo.x = (unsigned)ue[0] | ((unsigned)ue[1] << 16);
                uo.y = (unsigned)ue[2] | ((unsigned)ue[3] << 16);
                *(uint2*)&ubc[(size_t)((((wid * 2 + mi) * 2 + ni) * 64
                                        + lane) * 4)] = uo;
            }
    }
    __syncthreads();                                            // b4

    // ---- set2: Mtn = -mfma(Kt,R) -> TmpB ; P = mfma(U,Kt) -> global fp32
    {
        f32x4 aM[2][2], aP[2][2];
#pragma unroll
        for (int a = 0; a < 2; ++a)
#pragma unroll
            for (int b = 0; b < 2; ++b) {
                aM[a][b] = (f32x4){0.f, 0.f, 0.f, 0.f};
                aP[a][b] = (f32x4){0.f, 0.f, 0.f, 0.f};
            }
#pragma unroll
        for (int kh = 0; kh < 2; ++kh) {
            short8 kta[2], ua[2], rbb[2], ktb[2];
#pragma unroll
            for (int i = 0; i < 2; ++i) {
                kta[i] = ld_frag(KtB, ar0 + i * 16, kh * 4 + lcb);
                ua[i]  = ld_frag(Ub,  ar0 + i * 16, kh * 4 + lcb);
                rbb[i] = ld_frag(Rb,  br0 + i * 16, kh * 4 + lcb);
                ktb[i] = ld_frag(KtB, br0 + i * 16, kh * 4 + lcb);
            }
#pragma unroll
            for (int mi = 0; mi < 2; ++mi)
#pragma unroll
                for (int ni = 0; ni < 2; ++ni) {
                    aM[mi][ni] = __builtin_amdgcn_mfma_f32_16x16x32_bf16(
                        kta[mi], rbb[ni], aM[mi][ni], 0, 0, 0);
                    aP[mi][ni] = __builtin_amdgcn_mfma_f32_16x16x32_bf16(
                        ua[mi], ktb[ni], aP[mi][ni], 0, 0, 0);
                }
        }
#pragma unroll
        for (int mi = 0; mi < 2; ++mi)
#pragma unroll
            for (int ni = 0; ni < 2; ++ni) {
#pragma unroll
                for (int r = 0; r < 4; ++r)
                    st_sw(TmpB, or0 + mi * 16 + r, oc0 + ni * 16,
                          f2b(-aM[mi][ni][r]));
                *(f32x4*)&pfc[(size_t)((((wid * 2 + mi) * 2 + ni) * 64
                                        + lane) * 4)] = aP[mi][ni];
            }
    }
    __syncthreads();                                            // b5
    // disjoint wave pairs store Mtn (waves 0-1) and Rtn (waves 2-3)
    if (wid < 2) {
#pragma unroll
        for (int ni = 0; ni < 2; ++ni)
#pragma unroll
            for (int kh = 0; kh < 2; ++kh) {
                short8 v = ld_frag(TmpB, (wid & 1) * 32 + ni * 16 + (lane & 15),
                                   kh * 4 + lcb);
                *(short8*)&mtnc[(size_t)(((((wid & 1) * 2 + ni) * 2 + kh) * 64
                                          + lane) * 8)] = v;
            }
    } else {
#pragma unroll
        for (int ni = 0; ni < 2; ++ni)
#pragma unroll
            for (int kh = 0; kh < 2; ++kh) {
                short8 v = ld_frag(TmpA, (wid & 1) * 32 + ni * 16 + (lane & 15),
                                   kh * 4 + lcb);
                *(short8*)&rtnc[(size_t)(((((wid & 1) * 2 + ni) * 2 + kh) * 64
                                          + lane) * 8)] = v;
            }
    }
}

// ---------------------------------------------------------------------------
// Kernel 3 (seq): one block per chain; per chunk: store W_c, Delta = P_c +
// W_c*Mtn_c (acc-init P), accW += Delta. Wb double-buffered -> ONE barrier
// per chunk.
// ---------------------------------------------------------------------------
__global__ __launch_bounds__(256, 1) void ttt_seq_kernel(
    u16* __restrict__ mtnW, const float* __restrict__ pfA,
    const float* __restrict__ pfB)
{
    const int bh = blockIdx.x;
    const int bx0 = bh * NCH;
    const int tid = threadIdx.x, lane = tid & 63, wid = tid >> 6;
    const int wm = (wid >> 1) * 32, wn = (wid & 1) * 32;
    const int ar0 = wm + (lane & 15);
    const int lcb = lane >> 4;
    const int or0 = wm + ((lane >> 4) << 2);
    const int oc0 = wn + (lane & 15);
    const int wn2 = wid & 1;

    __shared__ u16 Wb[2][4096];

    f32x4 accW[2][2];
#pragma unroll
    for (int a = 0; a < 2; ++a)
#pragma unroll
        for (int b = 0; b < 2; ++b) accW[a][b] = (f32x4){0.f, 0.f, 0.f, 0.f};

    auto ldMtn = [&](int c, short8 (&m)[2][2]) {
        const u16* mb = mtnW + (size_t)(bx0 + c) * 4096;
#pragma unroll
        for (int ni = 0; ni < 2; ++ni)
#pragma unroll
            for (int kh = 0; kh < 2; ++kh)
                m[ni][kh] = *(const short8*)&mb[(size_t)(
                    (((wn2 * 2 + ni) * 2 + kh) * 64 + lane) * 8)];
    };
    auto ldPf = [&](int c, f32x4 (&p)[2][2]) {
        int bx = bx0 + c;
        const float* pb = (bx < 384) ? pfA + (size_t)bx * 4096
                                     : pfB + (size_t)(bx - 384) * 4096;
#pragma unroll
        for (int mi = 0; mi < 2; ++mi)
#pragma unroll
            for (int ni = 0; ni < 2; ++ni)
                p[mi][ni] = *(const f32x4*)&pb[(size_t)(
                    (((wid * 2 + mi) * 2 + ni) * 64 + lane) * 4)];
    };

    auto body = [&](int c, short8 (&cm)[2][2], f32x4 (&cp)[2][2],
                    short8 (&nm)[2][2], f32x4 (&np)[2][2]) {
        asm volatile("s_waitcnt vmcnt(0)" ::: "memory");
        u16* wcp = mtnW + (size_t)(bx0 + c) * 4096;
        u16* wl = &Wb[c & 1][0];
#pragma unroll
        for (int mi = 0; mi < 2; ++mi)
#pragma unroll
            for (int ni = 0; ni < 2; ++ni)
#pragma unroll
                for (int r = 0; r < 4; ++r) {
                    u16 v = f2b(accW[mi][ni][r]);
                    wcp[(or0 + mi * 16 + r) * 64 + oc0 + ni * 16] = v;
                    st_sw(wl, or0 + mi * 16 + r, oc0 + ni * 16, v);
                }
        if (c + 1 < NCH) { ldMtn(c + 1, nm); ldPf(c + 1, np); }
        __syncthreads();
        short8 wf[2][2];
#pragma unroll
        for (int mi = 0; mi < 2; ++mi)
#pragma unroll
            for (int kh = 0; kh < 2; ++kh)
                wf[mi][kh] = ld_frag(wl, ar0 + mi * 16, kh * 4 + lcb);
#pragma unroll
        for (int mi = 0; mi < 2; ++mi)
#pragma unroll
            for (int ni = 0; ni < 2; ++ni) {
                f32x4 d = cp[mi][ni];
#pragma unroll
                for (int kh = 0; kh < 2; ++kh)
                    d = __builtin_amdgcn_mfma_f32_16x16x32_bf16(
                        wf[mi][kh], cm[ni][kh], d, 0, 0, 0);
                accW[mi][ni] = accW[mi][ni] + d;
            }
        // no trailing barrier: next chunk writes the OTHER Wb buffer
    };

    short8 mA[2][2], mB[2][2];
    f32x4 pA[2][2], pB[2][2];
    ldMtn(0, mA); ldPf(0, pA);
    for (int c = 0; c < NCH; c += 2) {
        body(c,     mA, pA, mB, pB);
        body(c + 1, mB, pB, mA, pA);
    }
}

// ---------------------------------------------------------------------------
// Kernel 4 (outgen, parallel over 768 chunks):
//   S = stril(Q K^T); Etn = U + W * Rtn; Out = Q W^T + S Etn^T -> hidden.
// ---------------------------------------------------------------------------
__global__ __launch_bounds__(256) void ttt_outgen_kernel(
    const u16* __restrict__ qb, const u16* __restrict__ kb,
    const u16* __restrict__ wcg, const u16* __restrict__ rtng,
    const u16* __restrict__ ubg, u16* __restrict__ hid)
{
    const int bx = blockIdx.x;
    const int bh = bx >> 5, c = bx & 31;
    const int b = bh / HH, h = bh % HH;
    const u16* qc = qb + (size_t)bx * 4096;
    const u16* kc = kb + (size_t)bx * 4096;
    const u16* wcc = wcg + (size_t)bx * 4096;
    const u16* rtnc = rtng + (size_t)bx * 4096;
    const u16* ubc = ubg + (size_t)bx * 4096;
    u16* hch = hid + (size_t)b * TT * CC + h * DD;

    const int tid = threadIdx.x, lane = tid & 63, wid = tid >> 6;
    const int wm = (wid >> 1) * 32, wn = (wid & 1) * 32;
    const int ar0 = wm + (lane & 15);
    const int br0 = wn + (lane & 15);
    const int lcb = lane >> 4;
    const int or0 = wm + ((lane >> 4) << 2);
    const int oc0 = wn + (lane & 15);
    const int wn2 = wid & 1;

    __shared__ u16 Sl[4096], El[4096];

    short8 Qa[2][2], Kb2[2][2];
#pragma unroll
    for (int i = 0; i < 2; ++i)
#pragma unroll
        for (int kh = 0; kh < 2; ++kh) {
            Qa[i][kh]  = gfrag(qc, ar0 + i * 16, kh * 4 + lcb);
            Kb2[i][kh] = gfrag(kc, br0 + i * 16, kh * 4 + lcb);
        }
    f32x4 aS[2][2];
#pragma unroll
    for (int a = 0; a < 2; ++a)
#pragma unroll
        for (int d = 0; d < 2; ++d) aS[a][d] = (f32x4){0.f, 0.f, 0.f, 0.f};
#pragma unroll
    for (int kh = 0; kh < 2; ++kh)
#pragma unroll
        for (int mi = 0; mi < 2; ++mi)
#pragma unroll
            for (int ni = 0; ni < 2; ++ni)
                aS[mi][ni] = __builtin_amdgcn_mfma_f32_16x16x32_bf16(
                    Qa[mi][kh], Kb2[ni][kh], aS[mi][ni], 0, 0, 0);
#pragma unroll
    for (int mi = 0; mi < 2; ++mi)
#pragma unroll
        for (int ni = 0; ni < 2; ++ni)
#pragma unroll
            for (int r = 0; r < 4; ++r) {
                int t = or0 + mi * 16 + r, s = oc0 + ni * 16;
                st_sw(Sl, t, s, f2b((t > s) ? aS[mi][ni][r] : 0.f));
            }

    f32x4 aE[2][2];
#pragma unroll
    for (int mi = 0; mi < 2; ++mi)
#pragma unroll
        for (int ni = 0; ni < 2; ++ni) {
            uint2 uu = *(const uint2*)&ubc[(size_t)(
                (((wid * 2 + mi) * 2 + ni) * 64 + lane) * 4)];
            f32x4 e;
            e[0] = b2f((u16)(uu.x & 0xFFFF)); e[1] = b2f((u16)(uu.x >> 16));
            e[2] = b2f((u16)(uu.y & 0xFFFF)); e[3] = b2f((u16)(uu.y >> 16));
            aE[mi][ni] = e;
        }
    short8 Wa[2][2], Rtb[2][2];
#pragma unroll
    for (int i = 0; i < 2; ++i)
#pragma unroll
        for (int kh = 0; kh < 2; ++kh) {
            Wa[i][kh] = gfrag(wcc, ar0 + i * 16, kh * 4 + lcb);
            Rtb[i][kh] = *(const short8*)&rtnc[(size_t)(
                (((wn2 * 2 + i) * 2 + kh) * 64 + lane) * 8)];
        }
#pragma unroll
    for (int kh = 0; kh < 2; ++kh)
#pragma unroll
        for (int mi = 0; mi < 2; ++mi)
#pragma unroll
            for (int ni = 0; ni < 2; ++ni)
                aE[mi][ni] = __builtin_amdgcn_mfma_f32_16x16x32_bf16(
                    Wa[mi][kh], Rtb[ni][kh], aE[mi][ni], 0, 0, 0);
#pragma unroll
    for (int mi = 0; mi < 2; ++mi)
#pragma unroll
        for (int ni = 0; ni < 2; ++ni)
#pragma unroll
            for (int r = 0; r < 4; ++r)
                st_sw(El, or0 + mi * 16 + r, oc0 + ni * 16,
                      f2b(aE[mi][ni][r]));
    __syncthreads();

    f32x4 aO[2][2];
#pragma unroll
    for (int a = 0; a < 2; ++a)
#pragma unroll
        for (int d = 0; d < 2; ++d) aO[a][d] = (f32x4){0.f, 0.f, 0.f, 0.f};
#pragma unroll
    for (int kh = 0; kh < 2; ++kh) {
        short8 Wb2[2], Sa[2], Eb[2];
#pragma unroll
        for (int i = 0; i < 2; ++i) {
            Wb2[i] = gfrag(wcc, br0 + i * 16, kh * 4 + lcb);
            Sa[i]  = ld_frag(Sl, ar0 + i * 16, kh * 4 + lcb);
            Eb[i]  = ld_frag(El, br0 + i * 16, kh * 4 + lcb);
        }
#pragma unroll
        for (int mi = 0; mi < 2; ++mi)
#pragma unroll
            for (int ni = 0; ni < 2; ++ni) {
                aO[mi][ni] = __builtin_amdgcn_mfma_f32_16x16x32_bf16(
                    Qa[mi][kh], Wb2[ni], aO[mi][ni], 0, 0, 0);
                aO[mi][ni] = __builtin_amdgcn_mfma_f32_16x16x32_bf16(
                    Sa[mi], Eb[ni], aO[mi][ni], 0, 0, 0);
            }
    }
#pragma unroll
    for (int mi = 0; mi < 2; ++mi)
#pragma unroll
        for (int ni = 0; ni < 2; ++ni)
#pragma unroll
            for (int r = 0; r < 4; ++r)
                hch[(size_t)(c * CL + or0 + mi * 16 + r) * CC
                    + oc0 + ni * 16] = f2b(aO[mi][ni][r]);
}

// ---------------------------------------------------------------------------
// Kernel 5: output projection (bf16 MFMA, fp32 row-major out), XCD swizzled.
// ---------------------------------------------------------------------------
__global__ __launch_bounds__(256) void out_proj_kernel(
    const u16* __restrict__ hid, const u16* __restrict__ wo,
    float* __restrict__ out)
{
    const int bid = blockIdx.x;
    const int job = (bid & 7) * 24 + (bid >> 3);
    const int m0 = (job / 6) * 128;
    const int n0 = (job % 6) * 128;
    const int tid = threadIdx.x, lane = tid & 63, wid = tid >> 6;
    const int wm = (wid >> 1) * 64, wn = (wid & 1) * 64;

    __shared__ u16 As[128 * 64];
    __shared__ u16 Bs[128 * 64];

    f32x4 acc[4][4];
#pragma unroll
    for (int a = 0; a < 4; ++a)
#pragma unroll
        for (int b = 0; b < 4; ++b) acc[a][b] = (f32x4){0.f, 0.f, 0.f, 0.f};

    for (int kt = 0; kt < CC; kt += 64) {
#pragma unroll
        for (int i = 0; i < 4; ++i) {
            int slot = i * 256 + tid;
            int row = slot >> 3, c = slot & 7;
            int gc = c ^ (row & 7);
            GLOAD16(hid + (size_t)(m0 + row) * CC + kt + gc * 8,
                    (char*)As + slot * 16);
            GLOAD16(wo  + (size_t)(n0 + row) * CC + kt + gc * 8,
                    (char*)Bs + slot * 16);
        }
        asm volatile("s_waitcnt vmcnt(0)" ::: "memory");
        __syncthreads();

#pragma unroll
        for (int kh = 0; kh < 2; ++kh) {
            short8 af[4], bf[4];
            const int lc = kh * 4 + (lane >> 4);
#pragma unroll
            for (int mi = 0; mi < 4; ++mi) {
                int row = wm + mi * 16 + (lane & 15);
                af[mi] = *(const short8*)((const char*)As + row * 128
                                          + ((lc ^ (row & 7)) * 16));
            }
#pragma unroll
            for (int ni = 0; ni < 4; ++ni) {
                int row = wn + ni * 16 + (lane & 15);
                bf[ni] = *(const short8*)((const char*)Bs + row * 128
                                          + ((lc ^ (row & 7)) * 16));
            }
#pragma unroll
            for (int mi = 0; mi < 4; ++mi)
#pragma unroll
                for (int ni = 0; ni < 4; ++ni)
                    acc[mi][ni] = __builtin_amdgcn_mfma_f32_16x16x32_bf16(
                        af[mi], bf[ni], acc[mi][ni], 0, 0, 0);
        }
        __syncthreads();
    }

#pragma unroll
    for (int mi = 0; mi < 4; ++mi) {
#pragma unroll
        for (int ni = 0; ni < 4; ++ni) {
            int n = n0 + wn + ni * 16 + (lane & 15);
            int mbase = m0 + wm + mi * 16 + ((lane >> 4) << 2);
#pragma unroll
            for (int r = 0; r < 4; ++r)
                out[(size_t)(mbase + r) * CC + n] = acc[mi][ni][r];
        }
    }
}

// ---------------------------------------------------------------------------
extern "C" void kernel_launch(void* const* d_in, const int* in_sizes, int n_in,
                              void* d_out, int out_size, void* d_ws, size_t ws_size,
                              hipStream_t stream) {
    const float* x  = (const float*)d_in[0];
    const float* Wq = (const float*)d_in[1];
    const float* Wk = (const float*)d_in[2];
    const float* Wv = (const float*)d_in[3];
    const float* Wo = (const float*)d_in[4];
    const float* lr = (const float*)d_in[5];

    // workspace: 7*NQ + 4*WSZ u16. Aliases:
    //  slot2: vb -> Ub ; slot3: xb -> pfA(fp32) -> hid
    //  slot4: Mtn -> Wc ; slot6: pfB (fp32 half of P)
    u16* us   = (u16*)d_ws;
    u16* qb   = us;
    u16* kbw  = us + (size_t)NQ;
    u16* vbw  = us + (size_t)2 * NQ;    // -> Ub
    u16* xb   = us + (size_t)3 * NQ;    // -> pfA -> hid
    u16* mtnW = us + (size_t)4 * NQ;    // -> Wc
    u16* rtn  = us + (size_t)5 * NQ;
    float* pfB = (float*)(us + (size_t)6 * NQ);
    u16* wqb = us + (size_t)7 * NQ;
    u16* wkb = wqb + WSZ;
    u16* wvb = wkb + WSZ;
    u16* wob = wvb + WSZ;
    u16* ub  = vbw;
    float* pfA = (float*)xb;
    u16* hid = xb;

    // 0) fp32 -> bf16
    cvt5_kernel<<<dim3((NQ / 8 + 255) / 256, 5), 256, 0, stream>>>(
        x, Wq, Wk, Wv, Wo, xb, wqb, wkb, wvb, wob);

    // 1) q/k/v projections (bf16 out, [B,H,T,D], XCD-chunk swizzled)
    proj_qkv_kernel<<<dim3(576), 256, 0, stream>>>(
        xb, wqb, wkb, wvb, qb, kbw, vbw);

    // 2) prep: per-chunk U, P, Mtn, Rtn (768 parallel blocks, 3 blk/CU)
    ttt_prep3_kernel<<<dim3(NCHUNKS), 256, 0, stream>>>(
        kbw, vbw, lr, ub, pfA, pfB, mtnW, rtn);

    // 3) seq: W-chain only, 24 blocks, 1 gemm + 1 barrier per chunk
    ttt_seq_kernel<<<dim3(BB * HH), 256, 0, stream>>>(mtnW, pfA, pfB);

    // 4) outgen: per-chunk hidden output (768 parallel blocks)
    ttt_outgen_kernel<<<dim3(NCHUNKS), 256, 0, stream>>>(
        qb, kbw, mtnW, rtn, ub, hid);

    // 5) output projection (XCD-chunk swizzled)
    out_proj_kernel<<<dim3(192), 256, 0, stream>>>(
        hid, wob, (float*)d_out);
}